// Round 12
// baseline (53.693 us; speedup 1.0000x reference)
//
#include <hip/hip_runtime.h>
#include <cstddef>
#include <cstdint>

#define B_    8
#define T_EN_ 512
#define T_DE_ 128
#define D_    512
#define U_    256

// tanh(x) = 1 - 2/(exp2(C*x)+1), C = 2*log2(e)
#define TANH_C 2.8853900817779268f
#define L2E_   1.4426950408889634f
#define TANH_CLAMP 0.99999994f

typedef float f32x4 __attribute__((ext_vector_type(4)));
typedef short s16x8 __attribute__((ext_vector_type(8)));

__device__ __forceinline__ float fast_tanh_clamped(float x) {
  const float e = __builtin_amdgcn_exp2f(x * TANH_C);
  float t = fmaf(-2.0f, __builtin_amdgcn_rcpf(e + 1.0f), 1.0f);
  return fminf(fmaxf(t, -TANH_CLAMP), TANH_CLAMP);
}

__device__ __forceinline__ f32x4 pk4(float s) {
  f32x4 v; v[0] = s; v[1] = s; v[2] = s; v[3] = s; return v;
}

// split f32 -> bf16 hi (truncated) + bf16 lo (truncated remainder)
__device__ __forceinline__ void split_bf16(float x, short& hi, short& lo) {
  const unsigned u = __float_as_uint(x);
  hi = (short)(u >> 16);
  const float hf = __uint_as_float(u & 0xffff0000u);
  const float lf = x - hf;
  lo = (short)(__float_as_uint(lf) >> 16);
}

// ---------------------------------------------------------------------------
// K0: prepack w_en / w_de to bf16 hi/lo fragment planes (verified r5-r11).
// k-map in 32-k step s: k = s*32 + g*4 + (e&3) + 16*(e>>2), lane = g*16+n.
// ---------------------------------------------------------------------------
__global__ __launch_bounds__(256) void wprep_kernel(
    const float* __restrict__ w_en, const float* __restrict__ w_de,
    short* __restrict__ wen_hi, short* __restrict__ wen_lo,
    short* __restrict__ wde_hi, short* __restrict__ wde_lo) {
  const int blk = blockIdx.x, tid = threadIdx.x;
  const bool is_en = blk < 64;
  const int wq = blk & 63;
  const int s = wq >> 2, USq = wq & 3;
  const int n = tid & 15, g = (tid >> 4) & 3;
  const int US = USq * 4 + (tid >> 6);
  const float* W = is_en ? w_en : w_de;
  short* ph = is_en ? wen_hi : wde_hi;
  short* pl = is_en ? wen_lo : wde_lo;
  s16x8 h8, l8;
  #pragma unroll
  for (int e = 0; e < 8; ++e) {
    const int k = s * 32 + g * 4 + (e & 3) + 16 * (e >> 2);
    short h, l;
    split_bf16(W[(size_t)k * U_ + US * 16 + n], h, l);
    h8[e] = h; l8[e] = l;
  }
  const size_t ub = ((size_t)(s * 16 + US) * 4 + g) * 16 + n;
  *(s16x8*)(ph + ub * 8) = h8;
  *(s16x8*)(pl + ub * 8) = l8;
}

// ---------------------------------------------------------------------------
// K1: MFMA projections + tanh, r6-verified structure, but en/de activations
// are read DIRECTLY as row-major f32 (two float4 per frag: per wave-load the
// 64 lanes hit 16 rows x 64B contiguous segments) and split to bf16 hi/lo
// in-register -- the activation prepack round-trip (42 MB + a launch) is gone.
// 640 blocks x 256 thr:
//  en blocks [0,512): (b, uh, it): wave = 32u x 16i (2 acc). -> Et[b][u][i]
//  de blocks [512,640): (t64, uh): wave = 16j x 32u (2 acc). -> de_t[j][u]
// w frags from wprep planes (L2-hot), 2-stage prefetch, no LDS, no barriers.
// ---------------------------------------------------------------------------
__global__ __launch_bounds__(256) void mfma_proj_kernel(
    const float* __restrict__ en, const float* __restrict__ de,
    const short* __restrict__ wen_hi, const short* __restrict__ wen_lo,
    const short* __restrict__ wde_hi, const short* __restrict__ wde_lo,
    float* __restrict__ Et, float* __restrict__ de_t) {
  const int blk = blockIdx.x;
  const int tid = threadIdx.x;
  const int lane = tid & 63;
  const int wv = tid >> 6;
  const int rl = lane >> 4, cl = lane & 15;

  f32x4 acc[2] = {};

#define CONV(F0, F1, H, L)                                                \
  { _Pragma("unroll")                                                     \
    for (int e = 0; e < 8; ++e) {                                         \
      const float x = (e < 4) ? ((const float*)&(F0))[e]                  \
                              : ((const float*)&(F1))[e - 4];             \
      short hh, ll;                                                       \
      split_bf16(x, hh, ll);                                              \
      H[e] = hh; L[e] = ll; } }

  if (blk < 512) {
    const int b  = blk >> 6;
    const int uh = (blk >> 5) & 1;
    const int it = blk & 31;
    const int US0 = uh * 8 + wv * 2;
    // lane (g=rl, n=cl) owns en row it*16+cl, k-base rl*4
    const float* erow = en + ((size_t)(b * T_EN_ + it * 16 + cl)) * D_ + rl * 4;

    s16x8 wA[4], wB[4];
    float4 fA0, fA1, fB0, fB1;

#define LOAD_EN(WD, F0, F1, S)                                            \
    { const size_t o = ((size_t)((S) * 16 + US0) * 64 + lane) * 8;        \
      WD[0] = *(const s16x8*)(wen_hi + o);                                \
      WD[1] = *(const s16x8*)(wen_lo + o);                                \
      WD[2] = *(const s16x8*)(wen_hi + o + 512);                          \
      WD[3] = *(const s16x8*)(wen_lo + o + 512);                          \
      F0 = *(const float4*)(erow + (S) * 32);                             \
      F1 = *(const float4*)(erow + (S) * 32 + 16); }
#define MFMA_EN(WD, F0, F1)                                               \
    { s16x8 eh, el;                                                       \
      CONV(F0, F1, eh, el)                                                \
      acc[0] = __builtin_amdgcn_mfma_f32_16x16x32_bf16(WD[0], eh, acc[0], 0, 0, 0); \
      acc[0] = __builtin_amdgcn_mfma_f32_16x16x32_bf16(WD[0], el, acc[0], 0, 0, 0); \
      acc[0] = __builtin_amdgcn_mfma_f32_16x16x32_bf16(WD[1], eh, acc[0], 0, 0, 0); \
      acc[1] = __builtin_amdgcn_mfma_f32_16x16x32_bf16(WD[2], eh, acc[1], 0, 0, 0); \
      acc[1] = __builtin_amdgcn_mfma_f32_16x16x32_bf16(WD[2], el, acc[1], 0, 0, 0); \
      acc[1] = __builtin_amdgcn_mfma_f32_16x16x32_bf16(WD[3], eh, acc[1], 0, 0, 0); }

    LOAD_EN(wA, fA0, fA1, 0)
    for (int s = 0; s < 16; s += 2) {
      LOAD_EN(wB, fB0, fB1, s + 1)
      MFMA_EN(wA, fA0, fA1)
      if (s + 2 < 16) LOAD_EN(wA, fA0, fA1, s + 2)
      MFMA_EN(wB, fB0, fB1)
    }
#undef LOAD_EN
#undef MFMA_EN

    #pragma unroll
    for (int us = 0; us < 2; ++us) {
      #pragma unroll
      for (int r = 0; r < 4; ++r) {
        const int u = (US0 + us) * 16 + rl * 4 + r;
        const int i = it * 16 + cl;
        Et[((size_t)b * U_ + u) * T_EN_ + i] = fast_tanh_clamped(acc[us][r]);
      }
    }
  } else {
    const int y = blk - 512;
    const int t64 = y >> 1;
    const int uh = y & 1;
    const int US0 = uh * 8 + wv * 2;
    // lane (g=rl, n=cl) owns de row t64*16+cl, k-base rl*4
    const float* drow = de + ((size_t)(t64 * 16 + cl)) * D_ + rl * 4;

    s16x8 wA[4], wB[4];
    float4 fA0, fA1, fB0, fB1;

#define LOAD_DE(WD, F0, F1, S)                                            \
    { const size_t o = ((size_t)((S) * 16 + US0) * 64 + lane) * 8;        \
      WD[0] = *(const s16x8*)(wde_hi + o);                                \
      WD[1] = *(const s16x8*)(wde_lo + o);                                \
      WD[2] = *(const s16x8*)(wde_hi + o + 512);                          \
      WD[3] = *(const s16x8*)(wde_lo + o + 512);                          \
      F0 = *(const float4*)(drow + (S) * 32);                             \
      F1 = *(const float4*)(drow + (S) * 32 + 16); }
#define MFMA_DE(WD, F0, F1)                                               \
    { s16x8 ah, al;                                                       \
      CONV(F0, F1, ah, al)                                                \
      acc[0] = __builtin_amdgcn_mfma_f32_16x16x32_bf16(ah, WD[0], acc[0], 0, 0, 0); \
      acc[0] = __builtin_amdgcn_mfma_f32_16x16x32_bf16(ah, WD[1], acc[0], 0, 0, 0); \
      acc[0] = __builtin_amdgcn_mfma_f32_16x16x32_bf16(al, WD[0], acc[0], 0, 0, 0); \
      acc[1] = __builtin_amdgcn_mfma_f32_16x16x32_bf16(ah, WD[2], acc[1], 0, 0, 0); \
      acc[1] = __builtin_amdgcn_mfma_f32_16x16x32_bf16(ah, WD[3], acc[1], 0, 0, 0); \
      acc[1] = __builtin_amdgcn_mfma_f32_16x16x32_bf16(al, WD[2], acc[1], 0, 0, 0); }

    LOAD_DE(wA, fA0, fA1, 0)
    for (int s = 0; s < 16; s += 2) {
      LOAD_DE(wB, fB0, fB1, s + 1)
      MFMA_DE(wA, fA0, fA1)
      if (s + 2 < 16) LOAD_DE(wA, fA0, fA1, s + 2)
      MFMA_DE(wB, fB0, fB1)
    }
#undef LOAD_DE
#undef MFMA_DE

    #pragma unroll
    for (int us = 0; us < 2; ++us) {
      #pragma unroll
      for (int r = 0; r < 4; ++r) {
        const int j = t64 * 16 + rl * 4 + r;
        const int u = (US0 + us) * 16 + cl;
        de_t[(size_t)j * U_ + u] = fast_tanh_clamped(acc[us][r]);
      }
    }
  }
#undef CONV
}

// ---------------------------------------------------------------------------
// K2 v7: mu via 4-term rcp grouping of the tanh-addition identity:
//   per u-quad: d_i = A_i E_i + 1, n_i = nu_i E_i + nu_i A_i,
//   P12=d1d2, P34=d3d4, N = (n1d2+n2d1)P34 + (n3d4+n4d3)P12, D = P12 P34,
//   mu += N * rcp(D)   [exact algebra; 1 rcp / 4 terms vs v6's 1/2].
// Same verified v6 skeleton: grid 256 = jg*8 + b, 512 thr = 8 u-octant waves,
// wave covers 4 j x 512 i (8 i/lane as two f32x4 quads) x 32 u (8 quads).
// Partials mu_p[8][4][512] in LDS; waves 0..3 do masked softmax.
// ---------------------------------------------------------------------------
__global__ __launch_bounds__(512) void attn_mu_softmax_kernel(
    const float* __restrict__ Et, const float* __restrict__ de_t,
    const float* __restrict__ nu, const int* __restrict__ mask,
    float* __restrict__ out) {
  __shared__ f32x4 LA_s[4][U_ / 4];     // {A1..A4} per (j-local, u-quad)  4 KB
  __shared__ f32x4 LN_s[4][U_ / 4];     // {nu_i*A_i}                      4 KB
  __shared__ f32x4 nv4_s[U_ / 4];       // {nu1..nu4} per quad             1 KB
  __shared__ float mu_p[8][4][T_EN_];   // partial logits                 64 KB

  const int tid  = threadIdx.x;
  const int lane = tid & 63;
  const int w    = tid >> 6;           // u-octant 0..7
  const int b    = blockIdx.x & 7;
  const int jg   = blockIdx.x >> 3;    // 0..31
  const int j0   = jg * 4;

  // ---- prologue: per-(j, u-quad) constants ----
  if (tid < 256) {
    const int jl = tid >> 6;           // 0..3
    const int q  = tid & 63;
    const float4 Av = *(const float4*)(de_t + (size_t)(b * T_DE_ + j0 + jl) * U_ + 4 * q);
    const float4 nv = *(const float4*)(nu + 4 * q);
    f32x4 A, An;
    A[0] = Av.x; A[1] = Av.y; A[2] = Av.z; A[3] = Av.w;
    An[0] = Av.x * nv.x; An[1] = Av.y * nv.y;
    An[2] = Av.z * nv.z; An[3] = Av.w * nv.w;
    LA_s[jl][q] = A;
    LN_s[jl][q] = An;
    if (tid < 64) {
      f32x4 n4; n4[0] = nv.x; n4[1] = nv.y; n4[2] = nv.z; n4[3] = nv.w;
      nv4_s[q] = n4;
    }
  }
  __syncthreads();

  const int qb = w * 8;                // this wave's 8 quads (32 u)
  const float* __restrict__ EbA =
      Et + ((size_t)b * U_ + 4 * qb) * T_EN_ + lane * 4;

  const f32x4 one4 = {1.f, 1.f, 1.f, 1.f};
  f32x4 accA[4] = {}, accB[4] = {};    // [j-local] x {i-quad A, B}

  f32x4 E1Aa, E2Aa, E3Aa, E4Aa, E1Ba, E2Ba, E3Ba, E4Ba;
  f32x4 E1Ab, E2Ab, E3Ab, E4Ab, E1Bb, E2Bb, E3Bb, E4Bb;
  f32x4 LAa[4], LNa[4], LAb[4], LNb[4], nva, nvb;

#define LOADQ(SUF, P)                                                     \
  { const float* ep = EbA + (size_t)(4 * (P)) * T_EN_;                    \
    E1A##SUF = *(const f32x4*)(ep);                                       \
    E1B##SUF = *(const f32x4*)(ep + 256);                                 \
    E2A##SUF = *(const f32x4*)(ep + T_EN_);                               \
    E2B##SUF = *(const f32x4*)(ep + T_EN_ + 256);                         \
    E3A##SUF = *(const f32x4*)(ep + 2 * T_EN_);                           \
    E3B##SUF = *(const f32x4*)(ep + 2 * T_EN_ + 256);                     \
    E4A##SUF = *(const f32x4*)(ep + 3 * T_EN_);                           \
    E4B##SUF = *(const f32x4*)(ep + 3 * T_EN_ + 256);                     \
    LA##SUF[0] = LA_s[0][qb + (P)]; LN##SUF[0] = LN_s[0][qb + (P)];       \
    LA##SUF[1] = LA_s[1][qb + (P)]; LN##SUF[1] = LN_s[1][qb + (P)];       \
    LA##SUF[2] = LA_s[2][qb + (P)]; LN##SUF[2] = LN_s[2][qb + (P)];       \
    LA##SUF[3] = LA_s[3][qb + (P)]; LN##SUF[3] = LN_s[3][qb + (P)];       \
    nv##SUF = nv4_s[qb + (P)]; }

#define QCOMP(SUF, X)                                                     \
  { const f32x4 T1 = E1##X##SUF * nv##SUF[0];                             \
    const f32x4 T2 = E2##X##SUF * nv##SUF[1];                             \
    const f32x4 T3 = E3##X##SUF * nv##SUF[2];                             \
    const f32x4 T4 = E4##X##SUF * nv##SUF[3];                             \
    _Pragma("unroll")                                                     \
    for (int jl = 0; jl < 4; ++jl) {                                      \
      const f32x4 Ac = LA##SUF[jl];                                       \
      const f32x4 Nc = LN##SUF[jl];                                       \
      const f32x4 d1 = E1##X##SUF * Ac[0] + one4;                         \
      const f32x4 d2 = E2##X##SUF * Ac[1] + one4;                         \
      const f32x4 d3 = E3##X##SUF * Ac[2] + one4;                         \
      const f32x4 d4 = E4##X##SUF * Ac[3] + one4;                         \
      const f32x4 n1 = T1 + pk4(Nc[0]);                                   \
      const f32x4 n2 = T2 + pk4(Nc[1]);                                   \
      const f32x4 n3 = T3 + pk4(Nc[2]);                                   \
      const f32x4 n4 = T4 + pk4(Nc[3]);                                   \
      const f32x4 P12 = d1 * d2;                                          \
      const f32x4 P34 = d3 * d4;                                          \
      const f32x4 Nn12 = n1 * d2 + n2 * d1;                               \
      const f32x4 Nn34 = n3 * d4 + n4 * d3;                               \
      const f32x4 Nt = Nn12 * P34 + Nn34 * P12;                           \
      const f32x4 Dt = P12 * P34;                                         \
      f32x4 r;                                                            \
      r[0] = __builtin_amdgcn_rcpf(Dt[0]);                                \
      r[1] = __builtin_amdgcn_rcpf(Dt[1]);                                \
      r[2] = __builtin_amdgcn_rcpf(Dt[2]);                                \
      r[3] = __builtin_amdgcn_rcpf(Dt[3]);                                \
      acc##X[jl] = Nt * r + acc##X[jl];                                   \
    } }

  LOADQ(a, 0)
  for (int p0 = 0; p0 < 8; p0 += 2) {
    LOADQ(b, p0 + 1)
    QCOMP(a, A)
    QCOMP(a, B)
    if (p0 + 2 < 8) LOADQ(a, p0 + 2)
    QCOMP(b, A)
    QCOMP(b, B)
  }
#undef LOADQ
#undef QCOMP

  #pragma unroll
  for (int jl = 0; jl < 4; ++jl) {
    *(f32x4*)&mu_p[w][jl][lane * 4] = accA[jl];
    *(f32x4*)&mu_p[w][jl][256 + lane * 4] = accB[jl];
  }
  __syncthreads();

  // ---- combine 8 u-octant partials + masked softmax: waves 0..3, j each ----
  if (w < 4) {
    float vals[8];
    float mx = -3.0e38f;
    #pragma unroll
    for (int h = 0; h < 2; ++h) {
      f32x4 s = {0.f, 0.f, 0.f, 0.f};
      #pragma unroll
      for (int uo = 0; uo < 8; ++uo)
        s += *(const f32x4*)&mu_p[uo][w][h * 256 + lane * 4];
      const int4 mk = *(const int4*)(mask + b * T_EN_ + h * 256 + lane * 4);
      const float v0 = fmaf((float)mk.x - 1.f, 1.0e6f, s[0]);
      const float v1 = fmaf((float)mk.y - 1.f, 1.0e6f, s[1]);
      const float v2 = fmaf((float)mk.z - 1.f, 1.0e6f, s[2]);
      const float v3 = fmaf((float)mk.w - 1.f, 1.0e6f, s[3]);
      vals[h * 4 + 0] = v0; vals[h * 4 + 1] = v1;
      vals[h * 4 + 2] = v2; vals[h * 4 + 3] = v3;
      mx = fmaxf(mx, fmaxf(fmaxf(v0, v1), fmaxf(v2, v3)));
    }
    #pragma unroll
    for (int off = 32; off; off >>= 1) mx = fmaxf(mx, __shfl_xor(mx, off, 64));
    float sum = 0.0f;
    #pragma unroll
    for (int k = 0; k < 8; ++k) {
      const float e = __builtin_amdgcn_exp2f((vals[k] - mx) * L2E_);
      vals[k] = e;
      sum += e;
    }
    #pragma unroll
    for (int off = 32; off; off >>= 1) sum += __shfl_xor(sum, off, 64);
    const float inv = __builtin_amdgcn_rcpf(sum);
    float* op = out + (size_t)(b * T_DE_ + j0 + w) * T_EN_;
    #pragma unroll
    for (int h = 0; h < 2; ++h) {
      const float4 o = make_float4(vals[h * 4 + 0] * inv, vals[h * 4 + 1] * inv,
                                   vals[h * 4 + 2] * inv, vals[h * 4 + 3] * inv);
      *(float4*)(op + h * 256 + lane * 4) = o;
    }
  }
}

// ---------------------------------------------------------------------------
extern "C" void kernel_launch(void* const* d_in, const int* in_sizes, int n_in,
                              void* d_out, int out_size, void* d_ws, size_t ws_size,
                              hipStream_t stream) {
  const float* en   = (const float*)d_in[0];   // [B, T_EN, D]
  const float* de   = (const float*)d_in[1];   // [B, T_DE, D]
  const int*   mask = (const int*)d_in[2];     // [B, T_EN]
  const float* w_en = (const float*)d_in[3];   // [D, U]
  const float* w_de = (const float*)d_in[4];   // [D, U]
  const float* nu   = (const float*)d_in[5];   // [U, 1]
  float* out = (float*)d_out;                  // [B, T_DE, T_EN]

  // ws layout (6 MB)
  float* Et     = (float*)d_ws;                       // [B][U][T_EN]   4 MB
  float* de_t   = Et + (size_t)B_ * U_ * T_EN_;       // [B*T_DE][U]    1 MB
  short* p      = (short*)(de_t + (size_t)B_ * T_DE_ * U_);
  short* wen_hi = p;  p += 131072;                    // D*U shorts (256 KB)
  short* wen_lo = p;  p += 131072;
  short* wde_hi = p;  p += 131072;
  short* wde_lo = p;  p += 131072;

  wprep_kernel<<<dim3(128), 256, 0, stream>>>(
      w_en, w_de, wen_hi, wen_lo, wde_hi, wde_lo);
  mfma_proj_kernel<<<dim3(640), 256, 0, stream>>>(
      en, de, wen_hi, wen_lo, wde_hi, wde_lo, Et, de_t);
  attn_mu_softmax_kernel<<<dim3(256), 512, 0, stream>>>(
      Et, de_t, nu, mask, out);
}